// Round 4
// baseline (130.266 us; speedup 1.0000x reference)
//
#include <hip/hip_runtime.h>
#include <hip/hip_bf16.h>

// x:[16,64,128,128] f32 -> stats -> MLP -> per-sample kern[64,64,3,3] -> conv(pad=1)
// bf16 MFMA implicit GEMM. xT[b][y][130 xi][64 ci] bf16 (x-padded with zero cols),
// wT[b][co][tap][ci] bf16.
// R4: conv restructured for 2-resident blocks/CU: 32px x-tiles, ci-halves,
// global_load_lds staging with per-lane swizzled SOURCE (linear LDS dest),
// <=128 VGPR. kern_gen reads w2 once per (chunk,bq) for all 16 b.

#define B_ 16
#define CI_ 64
#define CO_ 64
#define HW_ 128
#define NPIX 16384
#define KEL 36864
#define XT_RS 8320          // 130 * 64 shorts per row

typedef __attribute__((ext_vector_type(4))) float f32x4;
typedef __attribute__((ext_vector_type(8))) short short8;

static __device__ __forceinline__ short bf16_of(float f) {
    __hip_bfloat16 h = __float2bfloat16(f);
    return *reinterpret_cast<short*>(&h);
}

// ---------- Kernel 1: transpose x -> xT bf16 [b][y][130][64]; partial stats ----------
__global__ __launch_bounds__(256) void xpose_stats(const float* __restrict__ x,
                                                   short* __restrict__ xT,
                                                   float* __restrict__ part) {
    int b = blockIdx.x, cig = blockIdx.y, pt = blockIdx.z;
    int t = threadIdx.x;
    int y = pt * 8 + (t >> 5);
    int x0 = (t & 31) * 4;

    const float* xb = x + ((size_t)(b * 64 + cig * 8)) * NPIX;
    short* xTb = xT + (size_t)b * 128 * XT_RS;

    float s[8], ss[8];
    f32x4 v[8];
    #pragma unroll
    for (int c = 0; c < 8; c++) {
        v[c] = *(const f32x4*)(xb + (size_t)c * NPIX + y * 128 + x0);
        s[c]  = v[c][0] + v[c][1] + v[c][2] + v[c][3];
        ss[c] = v[c][0]*v[c][0] + v[c][1]*v[c][1] + v[c][2]*v[c][2] + v[c][3]*v[c][3];
    }
    #pragma unroll
    for (int xi = 0; xi < 4; xi++) {
        short8 o;
        #pragma unroll
        for (int c = 0; c < 8; c++) o[c] = bf16_of(v[c][xi]);
        *(short8*)(xTb + ((size_t)(y * 130 + x0 + xi + 1)) * 64 + cig * 8) = o;
    }
    // zero-pad columns xi=0 and xi=129 (x halo) for this (b, cig, row range)
    if (t < 16) {
        int y2 = pt * 8 + (t & 7);
        int col = (t & 8) ? 129 : 0;
        short8 z = {0, 0, 0, 0, 0, 0, 0, 0};
        *(short8*)(xTb + ((size_t)(y2 * 130 + col)) * 64 + cig * 8) = z;
    }

    __shared__ float red[4][16];
    int lane = t & 63, w = t >> 6;
    #pragma unroll
    for (int c = 0; c < 8; c++) {
        float a = s[c], q = ss[c];
        for (int off = 32; off; off >>= 1) { a += __shfl_down(a, off); q += __shfl_down(q, off); }
        if (lane == 0) { red[w][c * 2] = a; red[w][c * 2 + 1] = q; }
    }
    __syncthreads();
    if (t < 16)
        part[((size_t)((b * 8 + cig) * 16 + pt)) * 16 + t] =
            red[0][t] + red[1][t] + red[2][t] + red[3][t];
}

// ---------- Kernel 2: stats+h for ALL b (redundant, cheap); wT = bf16(h@w2+b2) ----------
// grid (chunk=16, bq=4): each block reads its w2 slice ONCE, applies 4 b's h.
__global__ __launch_bounds__(256) void kern_gen(const float* __restrict__ part,
                                                const float* __restrict__ w1,
                                                const float* __restrict__ b1,
                                                const float* __restrict__ w2,
                                                const float* __restrict__ b2,
                                                short* __restrict__ wT) {
    int chunk = blockIdx.x, bq = blockIdx.y;
    __shared__ float st[16][128];
    __shared__ float h[16][32];
    int t = threadIdx.x;

    for (int id = t; id < 1024; id += 256) {       // all (b, ci) stats
        int b = id >> 6, ci = id & 63;
        const float* pb = part + ((size_t)((b * 8 + (ci >> 3)) * 16)) * 16 + (ci & 7) * 2;
        float s = 0.f, q = 0.f;
        #pragma unroll
        for (int p = 0; p < 16; p++) { s += pb[p * 16]; q += pb[p * 16 + 1]; }
        float mean = s * (1.f / NPIX);
        float var = fmaxf((q - s * mean) * (1.f / (NPIX - 1)), 0.f);
        st[b][ci] = mean;
        st[b][64 + ci] = sqrtf(var);
    }
    __syncthreads();
    for (int id = t; id < 512; id += 256) {        // all (b, 32) h
        int b = id >> 5, j = id & 31;
        float acc = b1[j];
        for (int i = 0; i < 128; i++) acc += st[b][i] * w1[i * 32 + j];
        h[b][j] = fmaxf(acc, 0.f);
    }
    __syncthreads();

    int jbase = chunk * 2304;
    float acc[9][4];
    #pragma unroll
    for (int tp = 0; tp < 9; tp++) {
        float bv = b2[jbase + tp * 256 + t];
        #pragma unroll
        for (int bb = 0; bb < 4; bb++) acc[tp][bb] = bv;
    }
    for (int i = 0; i < 32; i++) {
        const float* w2r = w2 + (size_t)i * KEL + jbase + t;
        float hv[4];
        #pragma unroll
        for (int bb = 0; bb < 4; bb++) hv[bb] = h[bq * 4 + bb][i];
        #pragma unroll
        for (int tp = 0; tp < 9; tp++) {
            float wv = w2r[tp * 256];
            #pragma unroll
            for (int bb = 0; bb < 4; bb++) acc[tp][bb] += hv[bb] * wv;
        }
    }
    #pragma unroll
    for (int tp = 0; tp < 9; tp++) {
        int j = jbase + tp * 256 + t;              // j = (co*64+ci)*9 + tap
        int co = j / 576;
        int rem = j - co * 576;
        int ci = rem / 9;
        int tap = rem - ci * 9;
        #pragma unroll
        for (int bb = 0; bb < 4; bb++)
            wT[(size_t)(bq * 4 + bb) * KEL + co * 576 + tap * 64 + ci] = bf16_of(acc[tp][bb]);
    }
}

// ---------- Kernel 3: conv via MFMA, 2-resident blocks ----------
// grid (xt=4, yt=32, b=16), 512 thr. Block: rows y0..y0+3, 32 px, all 64 co.
// LDS: 2 ci-halves x [6 rows][34 xi][4 slots] x 16B = 26 KB. DMA-staged with
// swizzled per-lane SOURCE (q = lg ^ ((xi>>1)&3)), linear LDS dest.
__global__ __launch_bounds__(512, 4) void conv_mfma(const short* __restrict__ xT,
                                                    const short* __restrict__ wT,
                                                    float* __restrict__ out) {
    __shared__ __align__(16) short xls[2][6528];   // 816 slots * 8 shorts per half

    int xt = blockIdx.x, ytile = blockIdx.y, b = blockIdx.z;
    int x0 = xt * 32, y0 = ytile * 4;
    int t = threadIdx.x;
    int l = t & 63, w = t >> 6;
    int ch = w & 1, r = w >> 1;
    int l15 = l & 15, lg = l >> 4;

    // zero OOB rows for boundary tiles (DMA lanes there are exec-masked off)
    if (ytile == 0 || ytile == 31) {
        int lr = (ytile == 0) ? 0 : 5;
        if (t < 136) {
            short8 z = {0, 0, 0, 0, 0, 0, 0, 0};
            *(short8*)&xls[0][(lr * 136 + t) * 8] = z;
            *(short8*)&xls[1][(lr * 136 + t) * 8] = z;
        }
    }

    // ---- issue both halves' DMA ----
    const short* xTb = xT + (size_t)b * 128 * XT_RS;
    #pragma unroll
    for (int h = 0; h < 2; h++) {
        #pragma unroll
        for (int it = 0; it < 2; it++) {
            int e = it * 512 + t;
            if (e < 816) {
                int lr = e / 136;
                int rem = e - lr * 136;
                int xi = rem >> 2, q = rem & 3;
                int y = y0 - 1 + lr;
                if ((unsigned)y < 128u) {
                    int o = h * 4 + (q ^ ((xi >> 1) & 3));
                    const short* src = xTb + (size_t)y * XT_RS + (x0 + xi) * 64 + o * 8;
                    short* dst = &xls[h][(it * 512 + (t & ~63)) * 8];
                    __builtin_amdgcn_global_load_lds(
                        (const __attribute__((address_space(1))) void*)src,
                        (__attribute__((address_space(3))) void*)dst, 16, 0, 0);
                }
            }
        }
    }
    asm volatile("s_waitcnt vmcnt(0)" ::: "memory");
    __syncthreads();

    // ---- compute: 2 ci-halves x 2 n-tiles x 9 taps, 2 co-frags per B-read ----
    const short* wTb = wT + ((size_t)(b * 64 + ch * 32 + l15)) * 576 + lg * 8;
    f32x4 acc[2][2];
    #pragma unroll
    for (int n = 0; n < 2; n++)
        #pragma unroll
        for (int g = 0; g < 2; g++) acc[n][g] = (f32x4){0.f, 0.f, 0.f, 0.f};

    #pragma unroll 1
    for (int h = 0; h < 2; h++) {
        short8 wf[2][9];
        #pragma unroll
        for (int g = 0; g < 2; g++)
            #pragma unroll
            for (int tap = 0; tap < 9; tap++)
                wf[g][tap] = *(const short8*)(wTb + g * 16 * 576 + tap * 64 + h * 32);
        const short* xh = &xls[h][0];
        #pragma unroll
        for (int n = 0; n < 2; n++) {
            #pragma unroll
            for (int tap = 0; tap < 9; tap++) {
                const int dy = tap / 3, dx = tap % 3;
                int xi = n * 16 + l15 + dx;
                short8 bf = *(const short8*)&xh[((r + dy) * 136 + xi * 4 + (lg ^ ((xi >> 1) & 3))) * 8];
                acc[n][0] = __builtin_amdgcn_mfma_f32_16x16x32_bf16(wf[0][tap], bf, acc[n][0], 0, 0, 0);
                acc[n][1] = __builtin_amdgcn_mfma_f32_16x16x32_bf16(wf[1][tap], bf, acc[n][1], 0, 0, 0);
            }
        }
    }

    // ---- store ----
    #pragma unroll
    for (int g = 0; g < 2; g++) {
        float* ob = out + ((size_t)(b * 64 + ch * 32 + g * 16 + lg * 4)) * NPIX
                        + (y0 + r) * 128 + x0 + l15;
        #pragma unroll
        for (int reg = 0; reg < 4; reg++)
            #pragma unroll
            for (int n = 0; n < 2; n++)
                ob[(size_t)reg * NPIX + n * 16] = acc[n][g][reg];
    }
}

extern "C" void kernel_launch(void* const* d_in, const int* in_sizes, int n_in,
                              void* d_out, int out_size, void* d_ws, size_t ws_size,
                              hipStream_t stream) {
    const float* x  = (const float*)d_in[0];
    const float* w1 = (const float*)d_in[1];
    const float* b1 = (const float*)d_in[2];
    const float* w2 = (const float*)d_in[3];
    const float* b2 = (const float*)d_in[4];
    float* out = (float*)d_out;

    float* part = (float*)d_ws;                                   // 128 KB
    short* wT = (short*)((char*)d_ws + 131072);                   // 1.18 MB
    short* xT = (short*)((char*)d_ws + 131072 + 1179648);         // 16*128*130*64*2 = 34.1 MB

    xpose_stats<<<dim3(B_, 8, 16), 256, 0, stream>>>(x, xT, part);
    kern_gen<<<dim3(16, 4), 256, 0, stream>>>(part, w1, b1, w2, b2, wT);
    conv_mfma<<<dim3(4, 32, B_), 512, 0, stream>>>(xT, wT, out);
}

// Round 5
// 99.878 us; speedup vs baseline: 1.3043x; 1.3043x over previous
//
#include <hip/hip_runtime.h>
#include <hip/hip_bf16.h>

// x:[16,64,128,128] f32 -> stats -> MLP -> per-sample kern[64,64,3,3] -> conv(pad=1)
// bf16 MFMA implicit GEMM. xT[b][y][130 xi][64 ci] bf16 (x-padded zero cols),
// wT[b][co][tap][ci] bf16.
// R5: conv = R3 structure (reg-preloaded weights, VGPR-staged swizzled LDS) but
// 64px tiles -> 50.7 KB LDS -> 2 blocks/CU, and weights split by K-half
// (wf[2][9] = 72 regs live, reloaded for kp=1) to stay under 128 VGPR.

#define B_ 16
#define CI_ 64
#define CO_ 64
#define HW_ 128
#define NPIX 16384
#define KEL 36864
#define XT_RS 8320          // 130 * 64 shorts per padded row

typedef __attribute__((ext_vector_type(4))) float f32x4;
typedef __attribute__((ext_vector_type(8))) short short8;

static __device__ __forceinline__ short bf16_of(float f) {
    __hip_bfloat16 h = __float2bfloat16(f);
    return *reinterpret_cast<short*>(&h);
}

// ---------- Kernel 1: transpose x -> xT bf16 [b][y][130][64]; partial stats ----------
__global__ __launch_bounds__(256) void xpose_stats(const float* __restrict__ x,
                                                   short* __restrict__ xT,
                                                   float* __restrict__ part) {
    int b = blockIdx.x, cig = blockIdx.y, pt = blockIdx.z;
    int t = threadIdx.x;
    int y = pt * 8 + (t >> 5);
    int x0 = (t & 31) * 4;

    const float* xb = x + ((size_t)(b * 64 + cig * 8)) * NPIX;
    short* xTb = xT + (size_t)b * 128 * XT_RS;

    float s[8], ss[8];
    f32x4 v[8];
    #pragma unroll
    for (int c = 0; c < 8; c++) {
        v[c] = *(const f32x4*)(xb + (size_t)c * NPIX + y * 128 + x0);
        s[c]  = v[c][0] + v[c][1] + v[c][2] + v[c][3];
        ss[c] = v[c][0]*v[c][0] + v[c][1]*v[c][1] + v[c][2]*v[c][2] + v[c][3]*v[c][3];
    }
    #pragma unroll
    for (int xi = 0; xi < 4; xi++) {
        short8 o;
        #pragma unroll
        for (int c = 0; c < 8; c++) o[c] = bf16_of(v[c][xi]);
        *(short8*)(xTb + ((size_t)(y * 130 + x0 + xi + 1)) * 64 + cig * 8) = o;
    }
    // zero-pad columns xi=0 and xi=129 (x halo)
    if (t < 16) {
        int y2 = pt * 8 + (t & 7);
        int col = (t & 8) ? 129 : 0;
        short8 z = {0, 0, 0, 0, 0, 0, 0, 0};
        *(short8*)(xTb + ((size_t)(y2 * 130 + col)) * 64 + cig * 8) = z;
    }

    __shared__ float red[4][16];
    int lane = t & 63, w = t >> 6;
    #pragma unroll
    for (int c = 0; c < 8; c++) {
        float a = s[c], q = ss[c];
        for (int off = 32; off; off >>= 1) { a += __shfl_down(a, off); q += __shfl_down(q, off); }
        if (lane == 0) { red[w][c * 2] = a; red[w][c * 2 + 1] = q; }
    }
    __syncthreads();
    if (t < 16)
        part[((size_t)((b * 8 + cig) * 16 + pt)) * 16 + t] =
            red[0][t] + red[1][t] + red[2][t] + red[3][t];
}

// ---------- Kernel 2: stats+h for ALL b (redundant, cheap); wT = bf16(h@w2+b2) ----------
__global__ __launch_bounds__(256) void kern_gen(const float* __restrict__ part,
                                                const float* __restrict__ w1,
                                                const float* __restrict__ b1,
                                                const float* __restrict__ w2,
                                                const float* __restrict__ b2,
                                                short* __restrict__ wT) {
    int chunk = blockIdx.x, bq = blockIdx.y;
    __shared__ float st[16][128];
    __shared__ float h[16][32];
    int t = threadIdx.x;

    for (int id = t; id < 1024; id += 256) {
        int b = id >> 6, ci = id & 63;
        const float* pb = part + ((size_t)((b * 8 + (ci >> 3)) * 16)) * 16 + (ci & 7) * 2;
        float s = 0.f, q = 0.f;
        #pragma unroll
        for (int p = 0; p < 16; p++) { s += pb[p * 16]; q += pb[p * 16 + 1]; }
        float mean = s * (1.f / NPIX);
        float var = fmaxf((q - s * mean) * (1.f / (NPIX - 1)), 0.f);
        st[b][ci] = mean;
        st[b][64 + ci] = sqrtf(var);
    }
    __syncthreads();
    for (int id = t; id < 512; id += 256) {
        int b = id >> 5, j = id & 31;
        float acc = b1[j];
        for (int i = 0; i < 128; i++) acc += st[b][i] * w1[i * 32 + j];
        h[b][j] = fmaxf(acc, 0.f);
    }
    __syncthreads();

    int jbase = chunk * 2304;
    float acc[9][4];
    #pragma unroll
    for (int tp = 0; tp < 9; tp++) {
        float bv = b2[jbase + tp * 256 + t];
        #pragma unroll
        for (int bb = 0; bb < 4; bb++) acc[tp][bb] = bv;
    }
    for (int i = 0; i < 32; i++) {
        const float* w2r = w2 + (size_t)i * KEL + jbase + t;
        float hv[4];
        #pragma unroll
        for (int bb = 0; bb < 4; bb++) hv[bb] = h[bq * 4 + bb][i];
        #pragma unroll
        for (int tp = 0; tp < 9; tp++) {
            float wv = w2r[tp * 256];
            #pragma unroll
            for (int bb = 0; bb < 4; bb++) acc[tp][bb] += hv[bb] * wv;
        }
    }
    #pragma unroll
    for (int tp = 0; tp < 9; tp++) {
        int j = jbase + tp * 256 + t;              // j = (co*64+ci)*9 + tap
        int co = j / 576;
        int rem = j - co * 576;
        int ci = rem / 9;
        int tap = rem - ci * 9;
        #pragma unroll
        for (int bb = 0; bb < 4; bb++)
            wT[(size_t)(bq * 4 + bb) * KEL + co * 576 + tap * 64 + ci] = bf16_of(acc[tp][bb]);
    }
}

// ---------- Kernel 3: conv via MFMA, 64px tiles, 2 blocks/CU ----------
// grid (xt=2, yt=32, b=16), 512 thr (8 waves). Wave w: ch=w&1 (32 co), r=w>>1.
// LDS [6][66][64] bf16 = 50.7 KB, XOR slot swizzle -> conflict-free b128 reads.
// Weights: wf[2 co-groups][9 taps] for one K-half resident (72 VGPR), reload for kp=1.
__global__ __launch_bounds__(512, 4) void conv_mfma(const short* __restrict__ xT,
                                                    const short* __restrict__ wT,
                                                    float* __restrict__ out) {
    __shared__ __align__(16) short xls[6][66][64];

    int xt = blockIdx.x, ytile = blockIdx.y, b = blockIdx.z;
    int x0 = xt * 64, y0 = ytile * 4;
    int t = threadIdx.x;
    int l = t & 63, w = t >> 6;
    int ch = w & 1, r = w >> 1;
    int l15 = l & 15, lg = l >> 4;

    // ---- stage 6 rows x 66 cols (from padded xT; y-OOB -> 0) ----
    const short* xTb = xT + (size_t)b * 128 * XT_RS;
    #pragma unroll
    for (int it = 0; it < 7; it++) {
        int e = it * 512 + t;
        if (e < 3168) {                     // 6*66*8
            int lr = e / 528;
            int rem = e - lr * 528;
            int xcol = rem >> 3, slot = rem & 7;
            int y = y0 - 1 + lr;
            short8 v = {0, 0, 0, 0, 0, 0, 0, 0};
            if ((unsigned)y < 128u)
                v = *(const short8*)(xTb + (size_t)y * XT_RS + (x0 + xcol) * 64 + slot * 8);
            *(short8*)&xls[lr][xcol][(slot ^ (xcol & 7)) << 3] = v;
        }
    }

    // ---- preload kp=0 weights (overlaps staging) ----
    const short* wTb = wT + ((size_t)(b * 64 + ch * 32 + l15)) * 576 + lg * 8;
    short8 wf[2][9];
    #pragma unroll
    for (int g = 0; g < 2; g++)
        #pragma unroll
        for (int tap = 0; tap < 9; tap++)
            wf[g][tap] = *(const short8*)(wTb + g * 16 * 576 + tap * 64);

    __syncthreads();

    f32x4 acc[4][2];
    #pragma unroll
    for (int n = 0; n < 4; n++)
        #pragma unroll
        for (int g = 0; g < 2; g++) acc[n][g] = (f32x4){0.f, 0.f, 0.f, 0.f};

    #pragma unroll
    for (int kp = 0; kp < 2; kp++) {
        if (kp == 1) {
            #pragma unroll
            for (int g = 0; g < 2; g++)
                #pragma unroll
                for (int tap = 0; tap < 9; tap++)
                    wf[g][tap] = *(const short8*)(wTb + g * 16 * 576 + tap * 64 + 32);
        }
        #pragma unroll
        for (int n = 0; n < 4; n++) {
            #pragma unroll
            for (int tap = 0; tap < 9; tap++) {
                const int dy = tap / 3, dx = tap % 3;
                int xi = n * 16 + l15 + dx;                       // 0..65
                short8 bf = *(const short8*)&xls[r + dy][xi][((kp * 4 + lg) ^ (xi & 7)) << 3];
                acc[n][0] = __builtin_amdgcn_mfma_f32_16x16x32_bf16(wf[0][tap], bf, acc[n][0], 0, 0, 0);
                acc[n][1] = __builtin_amdgcn_mfma_f32_16x16x32_bf16(wf[1][tap], bf, acc[n][1], 0, 0, 0);
            }
        }
    }

    // ---- store 2 co-groups x 4 regs x 4 n-tiles ----
    #pragma unroll
    for (int g = 0; g < 2; g++) {
        float* ob = out + ((size_t)(b * 64 + ch * 32 + g * 16 + lg * 4)) * NPIX
                        + (y0 + r) * 128 + x0 + l15;
        #pragma unroll
        for (int reg = 0; reg < 4; reg++)
            #pragma unroll
            for (int n = 0; n < 4; n++)
                ob[(size_t)reg * NPIX + n * 16] = acc[n][g][reg];
    }
}

extern "C" void kernel_launch(void* const* d_in, const int* in_sizes, int n_in,
                              void* d_out, int out_size, void* d_ws, size_t ws_size,
                              hipStream_t stream) {
    const float* x  = (const float*)d_in[0];
    const float* w1 = (const float*)d_in[1];
    const float* b1 = (const float*)d_in[2];
    const float* w2 = (const float*)d_in[3];
    const float* b2 = (const float*)d_in[4];
    float* out = (float*)d_out;

    float* part = (float*)d_ws;                                   // 128 KB
    short* wT = (short*)((char*)d_ws + 131072);                   // 1.18 MB
    short* xT = (short*)((char*)d_ws + 131072 + 1179648);         // 34.1 MB

    xpose_stats<<<dim3(B_, 8, 16), 256, 0, stream>>>(x, xT, part);
    kern_gen<<<dim3(16, 4), 256, 0, stream>>>(part, w1, b1, w2, b2, wT);
    conv_mfma<<<dim3(2, 32, B_), 512, 0, stream>>>(xT, wT, out);
}